// Round 6
// baseline (255.249 us; speedup 1.0000x reference)
//
#include <hip/hip_runtime.h>
#include <hip/hip_bf16.h>

// Problem constants
#define B_ 8
#define S_ 4096
#define H_ 512

using short8 = __attribute__((ext_vector_type(8))) short;
using f32x4  = __attribute__((ext_vector_type(4))) float;
using f32x8  = __attribute__((ext_vector_type(8))) float;
using u32x8  = __attribute__((ext_vector_type(8))) unsigned;

// ---------- helpers ----------
__device__ __forceinline__ float bf2f(unsigned u16) {
    return __uint_as_float(u16 << 16);
}
__device__ __forceinline__ unsigned pk2bf(float x, float y) {
    __hip_bfloat162 h = __float22bfloat162_rn(make_float2(x, y));  // v_cvt_pk_bf16_f32
    return *reinterpret_cast<unsigned*>(&h);
}
__device__ __forceinline__ unsigned short f2bf1(float x) {
    __hip_bfloat162 h = __float22bfloat162_rn(make_float2(x, 0.f));
    return *reinterpret_cast<unsigned short*>(&h);
}
__device__ __forceinline__ float softplus_f(float x) {
    float sp = __logf(1.0f + __expf(x));
    return x > 15.0f ? x : sp;
}

// ---------- GEMM: noise = softplus(A(32768x512) * W(1024x512)^T + b) ----------
// (byte-identical to the round-2 PASSING version)
// Output: QR interleaved ushort2 [32768 x 512 x {q,r}] bf16 in ws.
#define TM 128
#define TN 128
#define LDT 40   // padded LDS row length (bf16 elems): 32 + 8

__global__ __launch_bounds__(256)
void gemm_softplus(const float* __restrict__ A, const float* __restrict__ Wm,
                   const float* __restrict__ bias,
                   unsigned short* __restrict__ QR) {
    __shared__ unsigned short As[TM * LDT];
    __shared__ unsigned short Bs[TN * LDT];

    const int bid = blockIdx.x;
    const int bn  = bid & 7;     // N/128 = 8  (consecutive blocks share A strip -> L2 reuse)
    const int bm  = bid >> 3;    // 256
    const int t    = threadIdx.x;
    const int wave = t >> 6;
    const int lane = t & 63;
    const int wm = (wave >> 1) * 64;
    const int wn = (wave & 1) * 64;
    const int l15 = lane & 15;
    const int l4  = lane >> 4;   // 0..3

    const int m0 = bm * TM;
    const int n0 = bn * TN;

    f32x4 acc[4][4] = {};

    for (int kc = 0; kc < 512; kc += 32) {
        // stage A and B tiles (fp32 global -> bf16 LDS, packed HW convert)
#pragma unroll
        for (int i = 0; i < 4; ++i) {
            int g   = t + 256 * i;        // 0..1023
            int row = g >> 3;             // 0..127
            int c   = (g & 7) * 4;        // 0..28
            float4 va = *(const float4*)(A  + (size_t)(m0 + row) * 512 + kc + c);
            float4 vb = *(const float4*)(Wm + (size_t)(n0 + row) * 512 + kc + c);
            uint2 pa, pb;
            pa.x = pk2bf(va.x, va.y); pa.y = pk2bf(va.z, va.w);
            pb.x = pk2bf(vb.x, vb.y); pb.y = pk2bf(vb.z, vb.w);
            *(uint2*)&As[row * LDT + c] = pa;
            *(uint2*)&Bs[row * LDT + c] = pb;
        }
        __syncthreads();

        short8 af[4], bf[4];
#pragma unroll
        for (int i = 0; i < 4; ++i) {
            af[i] = *(const short8*)&As[(wm + i * 16 + l15) * LDT + l4 * 8];
            bf[i] = *(const short8*)&Bs[(wn + i * 16 + l15) * LDT + l4 * 8];
        }
#pragma unroll
        for (int i = 0; i < 4; ++i)
#pragma unroll
            for (int j = 0; j < 4; ++j)
                acc[i][j] = __builtin_amdgcn_mfma_f32_16x16x32_bf16(af[i], bf[j], acc[i][j], 0, 0, 0);
        __syncthreads();
    }

    // epilogue: bias + softplus, interleaved {q,r} bf16 store
#pragma unroll
    for (int i = 0; i < 4; ++i) {
        const int mbase = m0 + wm + i * 16 + l4 * 4;
#pragma unroll
        for (int j = 0; j < 4; ++j) {
            const int nloc = n0 + wn + j * 16 + l15;
            const float bs = bias[nloc];
#pragma unroll
            for (int r = 0; r < 4; ++r) {
                const int m = mbase + r;
                unsigned short v = f2bf1(softplus_f(acc[i][j][r] + bs));
                if (nloc < 512) QR[((size_t)m * 512 + nloc) * 2]             = v;
                else            QR[((size_t)m * 512 + (nloc - 512)) * 2 + 1] = v;
            }
        }
    }
}

// ---------- Chunked Kalman scan with warm-up, depth-2 software pipeline ----------
// 32 chunks of 128 steps; chunks >0 warm up for 128 steps from state=z, P=0.1.
// Two STATIC register buffer sets (z0/q0, z1/q1) -> no inter-buffer copies, so
// the compiler can keep the g+2 / g+3 loads in flight (partial vmcnt waits)
// while computing groups g / g+1.
__device__ __forceinline__ void loadg_f(const float* zp, const unsigned* qrp, int g,
                                        f32x8& Z, u32x8& Qr) {
    const int o = g * 4096;
#pragma unroll
    for (int u = 0; u < 8; ++u) { Z[u] = zp[o + u * 512]; Qr[u] = qrp[o + u * 512]; }
}
__device__ __forceinline__ void compg_f(const f32x8& Z, const u32x8& Qr, int g, int skipg,
                                        float& state, float& P, float* op) {
    const bool st = g >= skipg;
    const int boff = g * 4096;
#pragma unroll
    for (int u = 0; u < 8; ++u) {
        unsigned qr = Qr[u];
        float q = bf2f(qr & 0xffffu), r = bf2f(qr >> 16);
        float Pp = P + q, rr = r + 1e-6f;
        float K = Pp * __builtin_amdgcn_rcpf(Pp + rr);
        state = fmaf(K, Z[u] - state, state);
        P = rr * K;
        if (st) op[boff + u * 512] = state;
    }
}

__global__ __launch_bounds__(256)
void kalman_scan_f32(const float* __restrict__ z,
                     const unsigned* __restrict__ qrp_,
                     float* __restrict__ out) {
    const int t = threadIdx.x;
    const int hb = blockIdx.x & 1, b = (blockIdx.x >> 1) & 7, chunk = blockIdx.x >> 4; // 0..31
    const int h = (hb << 8) + t;
    const int s0 = chunk << 7;                  // chunk*128
    const int sw = chunk ? (s0 - 128) : 0;      // 128-step warm-up
    const size_t base = ((size_t)(b * S_ + sw)) * 512 + h;
    const int ng = ((s0 + 128) - sw) >> 3;      // 16 or 32 groups of 8
    const int skipg = (s0 - sw) >> 3;           // 0 or 16

    const float* zp = z + base;
    const unsigned* qrp = qrp_ + base;
    float* op = out + base;

    float state = zp[0];
    float P = 0.1f;

    f32x8 z0, z1; u32x8 q0, q1;
    loadg_f(zp, qrp, 0, z0, q0);
    loadg_f(zp, qrp, 1, z1, q1);
    for (int g = 0; g < ng; g += 2) {
        compg_f(z0, q0, g, skipg, state, P, op);
        if (g + 2 < ng) loadg_f(zp, qrp, g + 2, z0, q0);
        compg_f(z1, q1, g + 1, skipg, state, P, op);
        if (g + 3 < ng) loadg_f(zp, qrp, g + 3, z1, q1);
    }
}

// ================= launcher =================

extern "C" void kernel_launch(void* const* d_in, const int* in_sizes, int n_in,
                              void* d_out, int out_size, void* d_ws, size_t ws_size,
                              hipStream_t stream) {
    const float* lstm = (const float*)d_in[0];   // (8,4096,512) fp32
    const float* Wm   = (const float*)d_in[1];   // (1024,512)  fp32
    const float* bias = (const float*)d_in[2];   // (1024,)     fp32
    float* out = (float*)d_out;

    unsigned short* QRw = (unsigned short*)d_ws; // interleaved {q,r} bf16, 64 MB

    // GEMM + softplus: grid = (M/128)*(N/128) = 256*8 = 2048
    hipLaunchKernelGGL(gemm_softplus, dim3(2048), dim3(256), 0, stream,
                       lstm, Wm, bias, QRw);

    // Scan: 2(h-halves) * 8(batch) * 32(chunks) = 512 blocks of 256 threads
    hipLaunchKernelGGL(kalman_scan_f32, dim3(512), dim3(256), 0, stream,
                       lstm, (const unsigned*)QRw, out);
}